// Round 10
// baseline (220.037 us; speedup 1.0000x reference)
//
#include <hip/hip_runtime.h>

#define N_NODES 100000
#define N_EDGES 3200000
#define NB_F 782                       // fine buckets: 128 dst nodes each
#define RSZ 4992                       // per-bucket record window (max fill ~4500)
#define TILE 4096
#define NTILES ((N_EDGES + TILE - 1) / TILE)   // 782
#define EPT (TILE / 256)               // edges per thread per tile = 16

// ---------------------------------------------------------------------------
// Workspace layout (4-byte elements):
//   gcur      NB_F*16 ints   (cursor per bucket, one per 64B line; init kb*RSZ)
//   recs      NB_F*RSZ       (packed (local_dst<<17)|src; dense per bucket)
//   p1h  16N ushorts = bf16(x @ Wl1^T)   (3.2 MB, L2-resident)
//   q1b  16N floats  = x @ Wr1^T + b1
//   p2 / r2 / deg_inv   N floats each
// ---------------------------------------------------------------------------

__device__ __forceinline__ float bf2f_lo(unsigned int w) {
  return __uint_as_float(w << 16);
}
__device__ __forceinline__ float bf2f_hi(unsigned int w) {
  return __uint_as_float(w & 0xFFFF0000u);
}
__device__ __forceinline__ unsigned short f2bf(float f) {
  unsigned int b = __float_as_uint(f);
  return (unsigned short)((b + 0x7FFFu + ((b >> 16) & 1u)) >> 16);
}

__global__ __launch_bounds__(256) void k_init(int* __restrict__ gcur) {
  const int i = blockIdx.x * 256 + threadIdx.x;
  if (i < NB_F) gcur[i * 16] = i * RSZ;
}

__global__ __launch_bounds__(256) void k_proj1(
    const float* __restrict__ x, const float* __restrict__ Wl1,
    const float* __restrict__ Wr1, const float* __restrict__ b1,
    unsigned short* __restrict__ p1h, float* __restrict__ q1b) {
  __shared__ float sWl[16 * 32];
  __shared__ float sWr[16 * 32];
  __shared__ float sb[16];
  const int t = threadIdx.x;
  for (int i = t; i < 512; i += 256) {
    sWl[i] = Wl1[i];
    sWr[i] = Wr1[i];
  }
  if (t < 16) sb[t] = b1[t];
  __syncthreads();

  const int n = blockIdx.x * 256 + t;
  if (n >= N_NODES) return;

  float xr[32];
  const float4* xp = (const float4*)(x + (size_t)n * 32);
#pragma unroll
  for (int j = 0; j < 8; ++j) {
    float4 v = xp[j];
    xr[4 * j + 0] = v.x;
    xr[4 * j + 1] = v.y;
    xr[4 * j + 2] = v.z;
    xr[4 * j + 3] = v.w;
  }

  float pv[16], qv[16];
#pragma unroll
  for (int hh = 0; hh < 16; ++hh) {
    float a = 0.f, b = 0.f;
#pragma unroll
    for (int i = 0; i < 32; ++i) {
      a = fmaf(xr[i], sWl[hh * 32 + i], a);
      b = fmaf(xr[i], sWr[hh * 32 + i], b);
    }
    pv[hh] = a;
    qv[hh] = b + sb[hh];
  }

  unsigned int w[8];
#pragma unroll
  for (int j = 0; j < 8; ++j)
    w[j] = (unsigned int)f2bf(pv[2 * j]) |
           ((unsigned int)f2bf(pv[2 * j + 1]) << 16);
  uint4* pp = (uint4*)(p1h + (size_t)n * 16);
  pp[0] = make_uint4(w[0], w[1], w[2], w[3]);
  pp[1] = make_uint4(w[4], w[5], w[6], w[7]);

  float4* qp = (float4*)(q1b + (size_t)n * 16);
#pragma unroll
  for (int j = 0; j < 4; ++j)
    qp[j] = make_float4(qv[4 * j], qv[4 * j + 1], qv[4 * j + 2], qv[4 * j + 3]);
}

// tile counting-sort in LDS, then POSITION-ORDER write-out (one wave-store
// per 64B line -> L2 merges). TILE=4096 for grid balance (782 blocks).
__global__ __launch_bounds__(256) void k_bscatter(const int* __restrict__ ei,
                                                  int* __restrict__ gcur,
                                                  int* __restrict__ recs) {
  __shared__ int hist[1024];     // zero-padded past NB_F
  __shared__ int bstart[1024];   // exclusive scan; bstart[k>=NB_F]=nE sentinel
  __shared__ int cur[NB_F];
  __shared__ int rbase[NB_F];
  __shared__ int stage[TILE];
  __shared__ int seg[256];
  const int t = threadIdx.x;
  for (int i = t; i < 1024; i += 256) hist[i] = 0;
  __syncthreads();

  const int tb = blockIdx.x * TILE;
  const int nE = min(TILE, N_EDGES - tb);
  int ds[EPT], ss[EPT];
#pragma unroll
  for (int i = 0; i < EPT; ++i) {
    const int e = tb + t + i * 256;
    if (e < N_EDGES) {
      ss[i] = ei[e];
      ds[i] = ei[N_EDGES + e];
      atomicAdd(&hist[ds[i] >> 7], 1);
    } else {
      ds[i] = -1;
    }
  }
  __syncthreads();

  // exclusive scan of hist[1024] with 256 threads (4 elems/thread)
  const int s0 = hist[4 * t], s1 = hist[4 * t + 1], s2 = hist[4 * t + 2],
            s3 = hist[4 * t + 3];
  const int my = s0 + s1 + s2 + s3;
  seg[t] = my;
  __syncthreads();
#pragma unroll
  for (int o = 1; o < 256; o <<= 1) {
    const int a = (t >= o) ? seg[t - o] : 0;
    __syncthreads();
    seg[t] += a;
    __syncthreads();
  }
  const int ex = seg[t] - my;
  bstart[4 * t] = ex;
  bstart[4 * t + 1] = ex + s0;
  bstart[4 * t + 2] = ex + s0 + s1;
  bstart[4 * t + 3] = ex + s0 + s1 + s2;
  __syncthreads();

  // cursors + global reservation (unpadded)
  for (int i = t; i < NB_F; i += 256) {
    cur[i] = bstart[i];
    const int c = hist[i];
    if (c) rbase[i] = atomicAdd(&gcur[i * 16], c);
  }
  __syncthreads();

  // place records into LDS stage, grouped by bucket
#pragma unroll
  for (int i = 0; i < EPT; ++i) {
    if (ds[i] >= 0) {
      const int k = ds[i] >> 7;
      const int pos = atomicAdd(&cur[k], 1);
      stage[pos] = ((ds[i] & 127) << 17) | ss[i];
    }
  }
  __syncthreads();

  // write-out in position order; bucket via binary search over bstart
  for (int pos = t; pos < nE; pos += 256) {
    int lo = 0, hi = NB_F + 1;
    while (hi - lo > 1) {
      const int mid = (lo + hi) >> 1;
      if (bstart[mid] <= pos) lo = mid;
      else hi = mid;
    }
    const int k = lo;
    const int idx = rbase[k] + (pos - bstart[k]);
    if (idx < (k + 1) * RSZ) recs[idx] = stage[pos];
  }
}

// FUSED per-bucket sort + layer-1 aggregation. Sort bucket's records by local
// dst into LDS ssort (never touches global), then 4-lanes/node register
// accumulation with bf16 p1h gathers; fused relu + p2/r2/deg_inv epilogue.
__global__ __launch_bounds__(256) void k_sortagg1(
    const int* __restrict__ gcur, const int* __restrict__ recs,
    const unsigned short* __restrict__ p1h, const float* __restrict__ q1b,
    const float* __restrict__ Wl2, const float* __restrict__ Wr2,
    float* __restrict__ p2, float* __restrict__ r2,
    float* __restrict__ deg_inv) {
  __shared__ int hist[128];
  __shared__ int nstart[128];
  __shared__ int cur[128];
  __shared__ int ssort[RSZ];
  __shared__ float sWl[16], sWr[16];
  const int t = threadIdx.x;
  const int kb = blockIdx.x;
  const int b0 = kb * RSZ;
  const int gend = gcur[kb * 16];
  if (t < 128) hist[t] = 0;
  if (t < 16) {
    sWl[t] = Wl2[t];
    sWr[t] = Wr2[t];
  }
  __syncthreads();
  for (int r = b0 + t; r < gend; r += 256) atomicAdd(&hist[recs[r] >> 17], 1);
  __syncthreads();
  {
    int v = (t < 128) ? hist[t] : 0;
    if (t < 128) cur[t] = v;  // temporarily inclusive-scan in cur
    __syncthreads();
#pragma unroll
    for (int o = 1; o < 128; o <<= 1) {
      const int a = (t < 128 && t >= o) ? cur[t - o] : 0;
      __syncthreads();
      if (t < 128) cur[t] += a;
      __syncthreads();
    }
    if (t < 128) {
      const int ex = cur[t] - v;
      nstart[t] = ex;
      cur[t] = ex;
    }
  }
  __syncthreads();
  for (int r = b0 + t; r < gend; r += 256) {
    const int rec = recs[r];
    const int slot = atomicAdd(&cur[rec >> 17], 1);
    ssort[slot] = rec & 0x1FFFF;
  }
  __syncthreads();

  // aggregation: 2 rounds x 64 nodes, 4 lanes/node (lane owns 4 channels)
  const int c = t & 3;
  const unsigned short* pb = p1h + c * 4;
#pragma unroll
  for (int p = 0; p < 2; ++p) {
    const int local = p * 64 + (t >> 2);
    const int n = kb * 128 + local;
    if (n >= N_NODES) continue;
    const int st = nstart[local];
    const int k = hist[local];

    float a0 = 0.f, a1 = 0.f, a2 = 0.f, a3 = 0.f;
    int j = 0;
    for (; j + 4 <= k; j += 4) {
      const int s0 = ssort[st + j], s1 = ssort[st + j + 1],
                s2 = ssort[st + j + 2], s3 = ssort[st + j + 3];
      const uint2 w0 = *(const uint2*)(pb + (size_t)s0 * 16);
      const uint2 w1 = *(const uint2*)(pb + (size_t)s1 * 16);
      const uint2 w2 = *(const uint2*)(pb + (size_t)s2 * 16);
      const uint2 w3 = *(const uint2*)(pb + (size_t)s3 * 16);
      a0 += (bf2f_lo(w0.x) + bf2f_lo(w1.x)) + (bf2f_lo(w2.x) + bf2f_lo(w3.x));
      a1 += (bf2f_hi(w0.x) + bf2f_hi(w1.x)) + (bf2f_hi(w2.x) + bf2f_hi(w3.x));
      a2 += (bf2f_lo(w0.y) + bf2f_lo(w1.y)) + (bf2f_lo(w2.y) + bf2f_lo(w3.y));
      a3 += (bf2f_hi(w0.y) + bf2f_hi(w1.y)) + (bf2f_hi(w2.y) + bf2f_hi(w3.y));
    }
    for (; j < k; ++j) {
      const uint2 w = *(const uint2*)(pb + (size_t)ssort[st + j] * 16);
      a0 += bf2f_lo(w.x);
      a1 += bf2f_hi(w.x);
      a2 += bf2f_lo(w.y);
      a3 += bf2f_hi(w.y);
    }

    const float di = 1.f / fmaxf((float)k, 1.f);
    const float4 q = ((const float4*)(q1b + (size_t)n * 16))[c];
    const float h0 = fmaxf(fmaf(a0, di, q.x), 0.f);
    const float h1 = fmaxf(fmaf(a1, di, q.y), 0.f);
    const float h2 = fmaxf(fmaf(a2, di, q.z), 0.f);
    const float h3 = fmaxf(fmaf(a3, di, q.w), 0.f);
    float pa = h0 * sWl[4 * c] + h1 * sWl[4 * c + 1] + h2 * sWl[4 * c + 2] +
               h3 * sWl[4 * c + 3];
    float pbv = h0 * sWr[4 * c] + h1 * sWr[4 * c + 1] + h2 * sWr[4 * c + 2] +
                h3 * sWr[4 * c + 3];
    pa += __shfl_xor(pa, 1);
    pa += __shfl_xor(pa, 2);
    pbv += __shfl_xor(pbv, 1);
    pbv += __shfl_xor(pbv, 2);
    if (c == 0) {
      p2[n] = pa;
      r2[n] = pbv;
      deg_inv[n] = di;
    }
  }
}

// layer-2 aggregation + output epilogue: linear recs read, 1 LDS atomic per
// record into u[128] (p2 gathers are L2-resident 400 KB).
__global__ __launch_bounds__(256) void k_agg2out(
    const int* __restrict__ gcur, const int* __restrict__ recs,
    const float* __restrict__ p2, const float* __restrict__ r2,
    const float* __restrict__ deg_inv, const float* __restrict__ b2,
    float* __restrict__ out) {
  __shared__ float u[128];
  const int t = threadIdx.x;
  const int kb = blockIdx.x;
  const int b0 = kb * RSZ;
  const int gend = gcur[kb * 16];
  if (t < 128) u[t] = 0.f;
  __syncthreads();

  int r = b0 + t;
  for (; r + 768 < gend; r += 1024) {
    const int rec0 = recs[r];
    const int rec1 = recs[r + 256];
    const int rec2 = recs[r + 512];
    const int rec3 = recs[r + 768];
    const float v0 = p2[rec0 & 0x1FFFF];
    const float v1 = p2[rec1 & 0x1FFFF];
    const float v2 = p2[rec2 & 0x1FFFF];
    const float v3 = p2[rec3 & 0x1FFFF];
    atomicAdd(&u[rec0 >> 17], v0);
    atomicAdd(&u[rec1 >> 17], v1);
    atomicAdd(&u[rec2 >> 17], v2);
    atomicAdd(&u[rec3 >> 17], v3);
  }
  for (; r < gend; r += 256) {
    const int rec = recs[r];
    atomicAdd(&u[rec >> 17], p2[rec & 0x1FFFF]);
  }
  __syncthreads();
  const int n = kb * 128 + t;
  if (t < 128 && n < N_NODES)
    out[n] = fmaf(u[t], deg_inv[n], r2[n] + b2[0]);
}

extern "C" void kernel_launch(void* const* d_in, const int* in_sizes, int n_in,
                              void* d_out, int out_size, void* d_ws,
                              size_t ws_size, hipStream_t stream) {
  const float* x   = (const float*)d_in[0];
  const int*   ei  = (const int*)d_in[1];
  const float* Wl1 = (const float*)d_in[2];
  const float* Wr1 = (const float*)d_in[3];
  const float* b1  = (const float*)d_in[4];
  const float* Wl2 = (const float*)d_in[5];
  const float* Wr2 = (const float*)d_in[6];
  const float* b2  = (const float*)d_in[7];
  float* out = (float*)d_out;

  const size_t N = N_NODES;
  int* wi = (int*)d_ws;
  int* gcur = wi;                                      // NB_F*16
  int* recs = wi + NB_F * 16;                          // NB_F*RSZ
  unsigned short* p1h = (unsigned short*)(recs + (size_t)NB_F * RSZ);
  float* q1b     = (float*)(p1h + 16 * N);   // 16N ushorts = 8N words
  float* p2      = q1b + 16 * N;
  float* r2      = p2 + N;
  float* deg_inv = r2 + N;

  const int nodeBlocks = (N_NODES + 255) / 256;   // 391
  k_init<<<(NB_F + 255) / 256, 256, 0, stream>>>(gcur);
  k_proj1<<<nodeBlocks, 256, 0, stream>>>(x, Wl1, Wr1, b1, p1h, q1b);
  k_bscatter<<<NTILES, 256, 0, stream>>>(ei, gcur, recs);
  k_sortagg1<<<NB_F, 256, 0, stream>>>(gcur, recs, p1h, q1b, Wl2, Wr2, p2, r2,
                                       deg_inv);
  k_agg2out<<<NB_F, 256, 0, stream>>>(gcur, recs, p2, r2, deg_inv, b2, out);
}

// Round 11
// 204.063 us; speedup vs baseline: 1.0783x; 1.0783x over previous
//
#include <hip/hip_runtime.h>

#define N_NODES 100000
#define N_EDGES 3200000
#define NB_F 782                       // fine buckets: 128 dst nodes each
#define RSZ 4992                       // per-bucket record window (max fill ~4500)
#define TILE 6250
#define NTILES 512                     // 512*6250 == 3.2M exactly; 2 blocks/CU
#define MAXIT 25                       // ceil(TILE/256)
#define MAXB 20                        // ceil(RSZ/256) per-bucket iters

// ---------------------------------------------------------------------------
// Workspace layout (4-byte elements):
//   gcur  NB_F*16 ints  (cursor per bucket, one per 64B line; init kb*RSZ)
//   recs  NB_F*RSZ      (packed (local_dst<<17)|src; dense per bucket)
//   p1h   16N ushorts = bf16(x @ Wl1^T)   (3.2 MB, L2-resident)
//   q1b   16N floats  = x @ Wr1^T + b1
//   p2 / r2 / deg_inv   N floats each
// ---------------------------------------------------------------------------

__device__ __forceinline__ float bf2f_lo(unsigned int w) {
  return __uint_as_float(w << 16);
}
__device__ __forceinline__ float bf2f_hi(unsigned int w) {
  return __uint_as_float(w & 0xFFFF0000u);
}
__device__ __forceinline__ unsigned short f2bf(float f) {
  unsigned int b = __float_as_uint(f);
  return (unsigned short)((b + 0x7FFFu + ((b >> 16) & 1u)) >> 16);
}

__global__ __launch_bounds__(256) void k_init(int* __restrict__ gcur) {
  const int i = blockIdx.x * 256 + threadIdx.x;
  if (i < NB_F) gcur[i * 16] = i * RSZ;
}

__global__ __launch_bounds__(256) void k_proj1(
    const float* __restrict__ x, const float* __restrict__ Wl1,
    const float* __restrict__ Wr1, const float* __restrict__ b1,
    unsigned short* __restrict__ p1h, float* __restrict__ q1b) {
  __shared__ float sWl[16 * 32];
  __shared__ float sWr[16 * 32];
  __shared__ float sb[16];
  const int t = threadIdx.x;
  for (int i = t; i < 512; i += 256) {
    sWl[i] = Wl1[i];
    sWr[i] = Wr1[i];
  }
  if (t < 16) sb[t] = b1[t];
  __syncthreads();

  const int n = blockIdx.x * 256 + t;
  if (n >= N_NODES) return;

  float xr[32];
  const float4* xp = (const float4*)(x + (size_t)n * 32);
#pragma unroll
  for (int j = 0; j < 8; ++j) {
    float4 v = xp[j];
    xr[4 * j + 0] = v.x;
    xr[4 * j + 1] = v.y;
    xr[4 * j + 2] = v.z;
    xr[4 * j + 3] = v.w;
  }

  float pv[16], qv[16];
#pragma unroll
  for (int hh = 0; hh < 16; ++hh) {
    float a = 0.f, b = 0.f;
#pragma unroll
    for (int i = 0; i < 32; ++i) {
      a = fmaf(xr[i], sWl[hh * 32 + i], a);
      b = fmaf(xr[i], sWr[hh * 32 + i], b);
    }
    pv[hh] = a;
    qv[hh] = b + sb[hh];
  }

  unsigned int w[8];
#pragma unroll
  for (int j = 0; j < 8; ++j)
    w[j] = (unsigned int)f2bf(pv[2 * j]) |
           ((unsigned int)f2bf(pv[2 * j + 1]) << 16);
  uint4* pp = (uint4*)(p1h + (size_t)n * 16);
  pp[0] = make_uint4(w[0], w[1], w[2], w[3]);
  pp[1] = make_uint4(w[4], w[5], w[6], w[7]);

  float4* qp = (float4*)(q1b + (size_t)n * 16);
#pragma unroll
  for (int j = 0; j < 4; ++j)
    qp[j] = make_float4(qv[4 * j], qv[4 * j + 1], qv[4 * j + 2], qv[4 * j + 3]);
}

// tile counting-sort with RANK TRICK (1 LDS atomic/record): hist atomic
// returns the within-bucket rank; after scan, placement is atomic-free.
// Position-order write-out (one wave-store per 64B line). Grid 512 = 2/CU.
__global__ __launch_bounds__(256) void k_bscatter(const int* __restrict__ ei,
                                                  int* __restrict__ gcur,
                                                  int* __restrict__ recs) {
  __shared__ int hist[1024];   // counts, then overwritten with exclusive scan
  __shared__ int rbase[NB_F];
  __shared__ int stage[TILE];
  __shared__ int seg[256];
  const int t = threadIdx.x;
  for (int i = t; i < 1024; i += 256) hist[i] = 0;
  __syncthreads();

  const int tb = blockIdx.x * TILE;
  int rec[MAXIT], aux[MAXIT];  // aux = (bucket<<16) | rank
#pragma unroll
  for (int i = 0; i < MAXIT; ++i) {
    const int pos = t + i * 256;
    if (pos < TILE) {
      const int e = tb + pos;
      const int s = ei[e];
      const int d = ei[N_EDGES + e];
      const int k = d >> 7;
      const int rank = atomicAdd(&hist[k], 1);
      rec[i] = ((d & 127) << 17) | s;
      aux[i] = (k << 16) | rank;
    } else {
      aux[i] = -1;
    }
  }
  __syncthreads();

  // exclusive scan of hist[1024]; counts kept in regs, scan written in place
  const int s0 = hist[4 * t], s1 = hist[4 * t + 1], s2 = hist[4 * t + 2],
            s3 = hist[4 * t + 3];
  const int my = s0 + s1 + s2 + s3;
  seg[t] = my;
  __syncthreads();
#pragma unroll
  for (int o = 1; o < 256; o <<= 1) {
    const int a = (t >= o) ? seg[t - o] : 0;
    __syncthreads();
    seg[t] += a;
    __syncthreads();
  }
  const int ex = seg[t] - my;
  hist[4 * t] = ex;
  hist[4 * t + 1] = ex + s0;
  hist[4 * t + 2] = ex + s0 + s1;
  hist[4 * t + 3] = ex + s0 + s1 + s2;
  // global reservation for this tile's runs (counts still in regs)
  {
    const int b = 4 * t;
    if (b + 0 < NB_F && s0) rbase[b + 0] = atomicAdd(&gcur[(b + 0) * 16], s0);
    if (b + 1 < NB_F && s1) rbase[b + 1] = atomicAdd(&gcur[(b + 1) * 16], s1);
    if (b + 2 < NB_F && s2) rbase[b + 2] = atomicAdd(&gcur[(b + 2) * 16], s2);
    if (b + 3 < NB_F && s3) rbase[b + 3] = atomicAdd(&gcur[(b + 3) * 16], s3);
  }
  __syncthreads();

  // atomic-free placement: pos = bstart[k] + rank
#pragma unroll
  for (int i = 0; i < MAXIT; ++i) {
    if (aux[i] >= 0) {
      const int k = aux[i] >> 16;
      const int rank = aux[i] & 0xFFFF;
      stage[hist[k] + rank] = rec[i];
    }
  }
  __syncthreads();

  // write-out in position order; bucket via binary search over bstart(=hist)
  for (int pos = t; pos < TILE; pos += 256) {
    int lo = 0, hi = 1023;  // hist[>=NB_F] == TILE > pos
    while (hi - lo > 1) {
      const int mid = (lo + hi) >> 1;
      if (hist[mid] <= pos) lo = mid;
      else hi = mid;
    }
    const int k = lo;
    const int idx = rbase[k] + (pos - hist[k]);
    if (idx < (k + 1) * RSZ) recs[idx] = stage[pos];
  }
}

// FUSED per-bucket sort (rank trick, single recs read) + layer-1 aggregation:
// 2 lanes/node, uint4 (16B) bf16 gathers, register accumulation; fused
// relu + p2 = h@Wl2^T + r2 = h@Wr2^T + deg_inv. h never materialized.
__global__ __launch_bounds__(256) void k_sortagg1(
    const int* __restrict__ gcur, const int* __restrict__ recs,
    const unsigned short* __restrict__ p1h, const float* __restrict__ q1b,
    const float* __restrict__ Wl2, const float* __restrict__ Wr2,
    float* __restrict__ p2, float* __restrict__ r2,
    float* __restrict__ deg_inv) {
  __shared__ int hist[128];
  __shared__ int nstart[128];
  __shared__ int ssort[RSZ];
  __shared__ float sWl[16], sWr[16];
  const int t = threadIdx.x;
  const int kb = blockIdx.x;
  const int b0 = kb * RSZ;
  const int gend = gcur[kb * 16];
  if (t < 128) hist[t] = 0;
  if (t < 16) {
    sWl[t] = Wl2[t];
    sWr[t] = Wr2[t];
  }
  __syncthreads();

  int rc[MAXB], ax[MAXB];  // ax = (local<<13) | rank
#pragma unroll
  for (int i = 0; i < MAXB; ++i) {
    const int r = b0 + t + i * 256;
    if (r < gend) {
      const int rec = recs[r];
      const int local = rec >> 17;
      const int rank = atomicAdd(&hist[local], 1);
      rc[i] = rec & 0x1FFFF;
      ax[i] = (local << 13) | rank;
    } else {
      ax[i] = -1;
    }
  }
  __syncthreads();

  // exclusive scan of hist[128] -> nstart
  {
    int v = (t < 128) ? hist[t] : 0;
    if (t < 128) nstart[t] = v;
    __syncthreads();
#pragma unroll
    for (int o = 1; o < 128; o <<= 1) {
      const int a = (t < 128 && t >= o) ? nstart[t - o] : 0;
      __syncthreads();
      if (t < 128) nstart[t] += a;
      __syncthreads();
    }
    if (t < 128) nstart[t] -= v;
  }
  __syncthreads();

  // atomic-free placement into LDS
#pragma unroll
  for (int i = 0; i < MAXB; ++i) {
    if (ax[i] >= 0) ssort[nstart[ax[i] >> 13] + (ax[i] & 0x1FFF)] = rc[i];
  }
  __syncthreads();

  // aggregation: 2 lanes/node; lane owns 8 channels (one uint4 = 8 bf16)
  const int local = t >> 1;
  const int half = t & 1;
  const int n = kb * 128 + local;
  if (n >= N_NODES) return;
  const int st = nstart[local];
  const int k = hist[local];
  const unsigned short* pb = p1h + half * 8;

  float acc[8];
#pragma unroll
  for (int i = 0; i < 8; ++i) acc[i] = 0.f;
  int j = 0;
  for (; j + 4 <= k; j += 4) {
    const int s0 = ssort[st + j], s1 = ssort[st + j + 1],
              s2 = ssort[st + j + 2], s3 = ssort[st + j + 3];
    const uint4 w0 = *(const uint4*)(pb + (size_t)s0 * 16);
    const uint4 w1 = *(const uint4*)(pb + (size_t)s1 * 16);
    const uint4 w2 = *(const uint4*)(pb + (size_t)s2 * 16);
    const uint4 w3 = *(const uint4*)(pb + (size_t)s3 * 16);
    acc[0] += (bf2f_lo(w0.x) + bf2f_lo(w1.x)) + (bf2f_lo(w2.x) + bf2f_lo(w3.x));
    acc[1] += (bf2f_hi(w0.x) + bf2f_hi(w1.x)) + (bf2f_hi(w2.x) + bf2f_hi(w3.x));
    acc[2] += (bf2f_lo(w0.y) + bf2f_lo(w1.y)) + (bf2f_lo(w2.y) + bf2f_lo(w3.y));
    acc[3] += (bf2f_hi(w0.y) + bf2f_hi(w1.y)) + (bf2f_hi(w2.y) + bf2f_hi(w3.y));
    acc[4] += (bf2f_lo(w0.z) + bf2f_lo(w1.z)) + (bf2f_lo(w2.z) + bf2f_lo(w3.z));
    acc[5] += (bf2f_hi(w0.z) + bf2f_hi(w1.z)) + (bf2f_hi(w2.z) + bf2f_hi(w3.z));
    acc[6] += (bf2f_lo(w0.w) + bf2f_lo(w1.w)) + (bf2f_lo(w2.w) + bf2f_lo(w3.w));
    acc[7] += (bf2f_hi(w0.w) + bf2f_hi(w1.w)) + (bf2f_hi(w2.w) + bf2f_hi(w3.w));
  }
  for (; j < k; ++j) {
    const uint4 w = *(const uint4*)(pb + (size_t)ssort[st + j] * 16);
    acc[0] += bf2f_lo(w.x);
    acc[1] += bf2f_hi(w.x);
    acc[2] += bf2f_lo(w.y);
    acc[3] += bf2f_hi(w.y);
    acc[4] += bf2f_lo(w.z);
    acc[5] += bf2f_hi(w.z);
    acc[6] += bf2f_lo(w.w);
    acc[7] += bf2f_hi(w.w);
  }

  const float di = 1.f / fmaxf((float)k, 1.f);
  const float4* qp = (const float4*)(q1b + (size_t)n * 16 + half * 8);
  const float4 qa = qp[0], qb = qp[1];
  float h[8];
  h[0] = fmaxf(fmaf(acc[0], di, qa.x), 0.f);
  h[1] = fmaxf(fmaf(acc[1], di, qa.y), 0.f);
  h[2] = fmaxf(fmaf(acc[2], di, qa.z), 0.f);
  h[3] = fmaxf(fmaf(acc[3], di, qa.w), 0.f);
  h[4] = fmaxf(fmaf(acc[4], di, qb.x), 0.f);
  h[5] = fmaxf(fmaf(acc[5], di, qb.y), 0.f);
  h[6] = fmaxf(fmaf(acc[6], di, qb.z), 0.f);
  h[7] = fmaxf(fmaf(acc[7], di, qb.w), 0.f);
  float pa = 0.f, pbv = 0.f;
#pragma unroll
  for (int i = 0; i < 8; ++i) {
    pa = fmaf(h[i], sWl[half * 8 + i], pa);
    pbv = fmaf(h[i], sWr[half * 8 + i], pbv);
  }
  pa += __shfl_xor(pa, 1);
  pbv += __shfl_xor(pbv, 1);
  if (half == 0) {
    p2[n] = pa;
    r2[n] = pbv;
    deg_inv[n] = di;
  }
}

// layer-2 aggregation + output epilogue: linear recs read, 1 LDS atomic per
// record into u[128] (p2 gathers are L2-resident 400 KB).
__global__ __launch_bounds__(256) void k_agg2out(
    const int* __restrict__ gcur, const int* __restrict__ recs,
    const float* __restrict__ p2, const float* __restrict__ r2,
    const float* __restrict__ deg_inv, const float* __restrict__ b2,
    float* __restrict__ out) {
  __shared__ float u[128];
  const int t = threadIdx.x;
  const int kb = blockIdx.x;
  const int b0 = kb * RSZ;
  const int gend = gcur[kb * 16];
  if (t < 128) u[t] = 0.f;
  __syncthreads();

  int r = b0 + t;
  for (; r + 768 < gend; r += 1024) {
    const int rec0 = recs[r];
    const int rec1 = recs[r + 256];
    const int rec2 = recs[r + 512];
    const int rec3 = recs[r + 768];
    const float v0 = p2[rec0 & 0x1FFFF];
    const float v1 = p2[rec1 & 0x1FFFF];
    const float v2 = p2[rec2 & 0x1FFFF];
    const float v3 = p2[rec3 & 0x1FFFF];
    atomicAdd(&u[rec0 >> 17], v0);
    atomicAdd(&u[rec1 >> 17], v1);
    atomicAdd(&u[rec2 >> 17], v2);
    atomicAdd(&u[rec3 >> 17], v3);
  }
  for (; r < gend; r += 256) {
    const int rec = recs[r];
    atomicAdd(&u[rec >> 17], p2[rec & 0x1FFFF]);
  }
  __syncthreads();
  const int n = kb * 128 + t;
  if (t < 128 && n < N_NODES)
    out[n] = fmaf(u[t], deg_inv[n], r2[n] + b2[0]);
}

extern "C" void kernel_launch(void* const* d_in, const int* in_sizes, int n_in,
                              void* d_out, int out_size, void* d_ws,
                              size_t ws_size, hipStream_t stream) {
  const float* x   = (const float*)d_in[0];
  const int*   ei  = (const int*)d_in[1];
  const float* Wl1 = (const float*)d_in[2];
  const float* Wr1 = (const float*)d_in[3];
  const float* b1  = (const float*)d_in[4];
  const float* Wl2 = (const float*)d_in[5];
  const float* Wr2 = (const float*)d_in[6];
  const float* b2  = (const float*)d_in[7];
  float* out = (float*)d_out;

  const size_t N = N_NODES;
  int* wi = (int*)d_ws;
  int* gcur = wi;                                      // NB_F*16
  int* recs = wi + NB_F * 16;                          // NB_F*RSZ
  unsigned short* p1h = (unsigned short*)(recs + (size_t)NB_F * RSZ);
  float* q1b     = (float*)(p1h + 16 * N);   // 16N ushorts = 8N words
  float* p2      = q1b + 16 * N;
  float* r2      = p2 + N;
  float* deg_inv = r2 + N;

  const int nodeBlocks = (N_NODES + 255) / 256;   // 391
  k_init<<<(NB_F + 255) / 256, 256, 0, stream>>>(gcur);
  k_proj1<<<nodeBlocks, 256, 0, stream>>>(x, Wl1, Wr1, b1, p1h, q1b);
  k_bscatter<<<NTILES, 256, 0, stream>>>(ei, gcur, recs);
  k_sortagg1<<<NB_F, 256, 0, stream>>>(gcur, recs, p1h, q1b, Wl2, Wr2, p2, r2,
                                       deg_inv);
  k_agg2out<<<NB_F, 256, 0, stream>>>(gcur, recs, p2, r2, deg_inv, b2, out);
}

// Round 12
// 185.652 us; speedup vs baseline: 1.1852x; 1.0992x over previous
//
#include <hip/hip_runtime.h>

#define N_NODES 100000
#define N_EDGES 3200000
#define NB_F 782                       // fine buckets: 128 dst nodes each
#define RSZ 4992                       // per-bucket record window (max fill ~4500)
#define TILE 6250
#define NTILES 512                     // 512*6250 == 3.2M exactly; 2 blocks/CU
#define MAXIT 13                       // ceil(TILE/512)
#define MAXB 10                        // ceil(RSZ/512) per-bucket iters

// ---------------------------------------------------------------------------
// Workspace layout (4-byte elements):
//   gcur  NB_F*16 ints  (cursor per bucket, one per 64B line; init kb*RSZ)
//   recs  NB_F*RSZ      (packed (local_dst<<17)|src; dense per bucket)
//   p1h   16N ushorts = bf16(x @ Wl1^T)   (3.2 MB, L2-resident)
//   q1b   16N floats  = x @ Wr1^T + b1
//   p2 / r2 / deg_inv   N floats each
// ---------------------------------------------------------------------------

__device__ __forceinline__ float bf2f_lo(unsigned int w) {
  return __uint_as_float(w << 16);
}
__device__ __forceinline__ float bf2f_hi(unsigned int w) {
  return __uint_as_float(w & 0xFFFF0000u);
}
__device__ __forceinline__ unsigned short f2bf(float f) {
  unsigned int b = __float_as_uint(f);
  return (unsigned short)((b + 0x7FFFu + ((b >> 16) & 1u)) >> 16);
}

__global__ __launch_bounds__(256) void k_init(int* __restrict__ gcur) {
  const int i = blockIdx.x * 256 + threadIdx.x;
  if (i < NB_F) gcur[i * 16] = i * RSZ;
}

__global__ __launch_bounds__(256) void k_proj1(
    const float* __restrict__ x, const float* __restrict__ Wl1,
    const float* __restrict__ Wr1, const float* __restrict__ b1,
    unsigned short* __restrict__ p1h, float* __restrict__ q1b) {
  __shared__ float sWl[16 * 32];
  __shared__ float sWr[16 * 32];
  __shared__ float sb[16];
  const int t = threadIdx.x;
  for (int i = t; i < 512; i += 256) {
    sWl[i] = Wl1[i];
    sWr[i] = Wr1[i];
  }
  if (t < 16) sb[t] = b1[t];
  __syncthreads();

  const int n = blockIdx.x * 256 + t;
  if (n >= N_NODES) return;

  float xr[32];
  const float4* xp = (const float4*)(x + (size_t)n * 32);
#pragma unroll
  for (int j = 0; j < 8; ++j) {
    float4 v = xp[j];
    xr[4 * j + 0] = v.x;
    xr[4 * j + 1] = v.y;
    xr[4 * j + 2] = v.z;
    xr[4 * j + 3] = v.w;
  }

  float pv[16], qv[16];
#pragma unroll
  for (int hh = 0; hh < 16; ++hh) {
    float a = 0.f, b = 0.f;
#pragma unroll
    for (int i = 0; i < 32; ++i) {
      a = fmaf(xr[i], sWl[hh * 32 + i], a);
      b = fmaf(xr[i], sWr[hh * 32 + i], b);
    }
    pv[hh] = a;
    qv[hh] = b + sb[hh];
  }

  unsigned int w[8];
#pragma unroll
  for (int j = 0; j < 8; ++j)
    w[j] = (unsigned int)f2bf(pv[2 * j]) |
           ((unsigned int)f2bf(pv[2 * j + 1]) << 16);
  uint4* pp = (uint4*)(p1h + (size_t)n * 16);
  pp[0] = make_uint4(w[0], w[1], w[2], w[3]);
  pp[1] = make_uint4(w[4], w[5], w[6], w[7]);

  float4* qp = (float4*)(q1b + (size_t)n * 16);
#pragma unroll
  for (int j = 0; j < 4; ++j)
    qp[j] = make_float4(qv[4 * j], qv[4 * j + 1], qv[4 * j + 2], qv[4 * j + 3]);
}

// tile counting-sort with RANK TRICK (1 LDS atomic/record); 512 threads for
// 16 waves/CU latency hiding. Position-order write-out (L2-merged lines).
__global__ __launch_bounds__(512) void k_bscatter(const int* __restrict__ ei,
                                                  int* __restrict__ gcur,
                                                  int* __restrict__ recs) {
  __shared__ int hist[1024];   // counts, then overwritten with exclusive scan
  __shared__ int rbase[NB_F];
  __shared__ int stage[TILE];
  __shared__ int seg[512];
  const int t = threadIdx.x;
  for (int i = t; i < 1024; i += 512) hist[i] = 0;
  __syncthreads();

  const int tb = blockIdx.x * TILE;
  int rec[MAXIT], aux[MAXIT];  // aux = (bucket<<16) | rank
#pragma unroll
  for (int i = 0; i < MAXIT; ++i) {
    const int pos = t + i * 512;
    if (pos < TILE) {
      const int e = tb + pos;
      const int s = ei[e];
      const int d = ei[N_EDGES + e];
      const int k = d >> 7;
      const int rank = atomicAdd(&hist[k], 1);
      rec[i] = ((d & 127) << 17) | s;
      aux[i] = (k << 16) | rank;
    } else {
      aux[i] = -1;
    }
  }
  __syncthreads();

  // exclusive scan of hist[1024] with 512 threads (2 elems/thread)
  const int s0 = hist[2 * t], s1 = hist[2 * t + 1];
  const int my = s0 + s1;
  seg[t] = my;
  __syncthreads();
#pragma unroll
  for (int o = 1; o < 512; o <<= 1) {
    const int a = (t >= o) ? seg[t - o] : 0;
    __syncthreads();
    seg[t] += a;
    __syncthreads();
  }
  const int ex = seg[t] - my;
  hist[2 * t] = ex;
  hist[2 * t + 1] = ex + s0;
  // global reservation for this tile's runs (counts still in regs)
  {
    const int b = 2 * t;
    if (b + 0 < NB_F && s0) rbase[b + 0] = atomicAdd(&gcur[(b + 0) * 16], s0);
    if (b + 1 < NB_F && s1) rbase[b + 1] = atomicAdd(&gcur[(b + 1) * 16], s1);
  }
  __syncthreads();

  // atomic-free placement: pos = bstart[k] + rank
#pragma unroll
  for (int i = 0; i < MAXIT; ++i) {
    if (aux[i] >= 0) {
      const int k = aux[i] >> 16;
      const int rank = aux[i] & 0xFFFF;
      stage[hist[k] + rank] = rec[i];
    }
  }
  __syncthreads();

  // write-out in position order; bucket via binary search over bstart(=hist)
  for (int pos = t; pos < TILE; pos += 512) {
    int lo = 0, hi = 1023;  // hist[>=NB_F] == TILE > pos
    while (hi - lo > 1) {
      const int mid = (lo + hi) >> 1;
      if (hist[mid] <= pos) lo = mid;
      else hi = mid;
    }
    const int k = lo;
    const int idx = rbase[k] + (pos - hist[k]);
    if (idx < (k + 1) * RSZ) recs[idx] = stage[pos];
  }
}

// FUSED per-bucket sort (rank trick) + layer-1 aggregation, 512 threads:
// 4 lanes/node = (channel-half, edge-parity); each lane walks k/2 edges with
// 16B bf16 gathers -> half the dependent-chain length of the 2-lane version.
__global__ __launch_bounds__(512) void k_sortagg1(
    const int* __restrict__ gcur, const int* __restrict__ recs,
    const unsigned short* __restrict__ p1h, const float* __restrict__ q1b,
    const float* __restrict__ Wl2, const float* __restrict__ Wr2,
    float* __restrict__ p2, float* __restrict__ r2,
    float* __restrict__ deg_inv) {
  __shared__ int hist[128];
  __shared__ int nstart[128];
  __shared__ int ssort[RSZ];
  __shared__ float sWl[16], sWr[16];
  const int t = threadIdx.x;
  const int kb = blockIdx.x;
  const int b0 = kb * RSZ;
  const int gend = gcur[kb * 16];
  if (t < 128) hist[t] = 0;
  if (t < 16) {
    sWl[t] = Wl2[t];
    sWr[t] = Wr2[t];
  }
  __syncthreads();

  int rc[MAXB], ax[MAXB];  // ax = (local<<13) | rank
#pragma unroll
  for (int i = 0; i < MAXB; ++i) {
    const int r = b0 + t + i * 512;
    if (r < gend) {
      const int rec = recs[r];
      const int local = rec >> 17;
      const int rank = atomicAdd(&hist[local], 1);
      rc[i] = rec & 0x1FFFF;
      ax[i] = (local << 13) | rank;
    } else {
      ax[i] = -1;
    }
  }
  __syncthreads();

  // exclusive scan of hist[128] -> nstart
  {
    int v = (t < 128) ? hist[t] : 0;
    if (t < 128) nstart[t] = v;
    __syncthreads();
#pragma unroll
    for (int o = 1; o < 128; o <<= 1) {
      const int a = (t < 128 && t >= o) ? nstart[t - o] : 0;
      __syncthreads();
      if (t < 128) nstart[t] += a;
      __syncthreads();
    }
    if (t < 128) nstart[t] -= v;
  }
  __syncthreads();

  // atomic-free placement into LDS
#pragma unroll
  for (int i = 0; i < MAXB; ++i) {
    if (ax[i] >= 0) ssort[nstart[ax[i] >> 13] + (ax[i] & 0x1FFF)] = rc[i];
  }
  __syncthreads();

  // aggregation: 4 lanes/node; quad = (edge-parity<<1)|channel-half
  const int local = t >> 2;
  const int quad = t & 3;
  const int half = quad & 1;   // channel half (8 channels)
  const int epar = quad >> 1;  // edge parity
  const int n = kb * 128 + local;
  if (n >= N_NODES) return;
  const int st = nstart[local];
  const int k = hist[local];
  const unsigned short* pb = p1h + half * 8;

  float acc[8];
#pragma unroll
  for (int i = 0; i < 8; ++i) acc[i] = 0.f;
  int j = epar;
  for (; j + 6 < k; j += 8) {
    const int s0 = ssort[st + j], s1 = ssort[st + j + 2],
              s2 = ssort[st + j + 4], s3 = ssort[st + j + 6];
    const uint4 w0 = *(const uint4*)(pb + (size_t)s0 * 16);
    const uint4 w1 = *(const uint4*)(pb + (size_t)s1 * 16);
    const uint4 w2 = *(const uint4*)(pb + (size_t)s2 * 16);
    const uint4 w3 = *(const uint4*)(pb + (size_t)s3 * 16);
    acc[0] += (bf2f_lo(w0.x) + bf2f_lo(w1.x)) + (bf2f_lo(w2.x) + bf2f_lo(w3.x));
    acc[1] += (bf2f_hi(w0.x) + bf2f_hi(w1.x)) + (bf2f_hi(w2.x) + bf2f_hi(w3.x));
    acc[2] += (bf2f_lo(w0.y) + bf2f_lo(w1.y)) + (bf2f_lo(w2.y) + bf2f_lo(w3.y));
    acc[3] += (bf2f_hi(w0.y) + bf2f_hi(w1.y)) + (bf2f_hi(w2.y) + bf2f_hi(w3.y));
    acc[4] += (bf2f_lo(w0.z) + bf2f_lo(w1.z)) + (bf2f_lo(w2.z) + bf2f_lo(w3.z));
    acc[5] += (bf2f_hi(w0.z) + bf2f_hi(w1.z)) + (bf2f_hi(w2.z) + bf2f_hi(w3.z));
    acc[6] += (bf2f_lo(w0.w) + bf2f_lo(w1.w)) + (bf2f_lo(w2.w) + bf2f_lo(w3.w));
    acc[7] += (bf2f_hi(w0.w) + bf2f_hi(w1.w)) + (bf2f_hi(w2.w) + bf2f_hi(w3.w));
  }
  for (; j < k; j += 2) {
    const uint4 w = *(const uint4*)(pb + (size_t)ssort[st + j] * 16);
    acc[0] += bf2f_lo(w.x);
    acc[1] += bf2f_hi(w.x);
    acc[2] += bf2f_lo(w.y);
    acc[3] += bf2f_hi(w.y);
    acc[4] += bf2f_lo(w.z);
    acc[5] += bf2f_hi(w.z);
    acc[6] += bf2f_lo(w.w);
    acc[7] += bf2f_hi(w.w);
  }
  // combine edge parities (lanes differing in bit 1)
#pragma unroll
  for (int i = 0; i < 8; ++i) acc[i] += __shfl_xor(acc[i], 2);

  const float di = 1.f / fmaxf((float)k, 1.f);
  const float4* qp = (const float4*)(q1b + (size_t)n * 16 + half * 8);
  const float4 qa = qp[0], qb = qp[1];
  float h[8];
  h[0] = fmaxf(fmaf(acc[0], di, qa.x), 0.f);
  h[1] = fmaxf(fmaf(acc[1], di, qa.y), 0.f);
  h[2] = fmaxf(fmaf(acc[2], di, qa.z), 0.f);
  h[3] = fmaxf(fmaf(acc[3], di, qa.w), 0.f);
  h[4] = fmaxf(fmaf(acc[4], di, qb.x), 0.f);
  h[5] = fmaxf(fmaf(acc[5], di, qb.y), 0.f);
  h[6] = fmaxf(fmaf(acc[6], di, qb.z), 0.f);
  h[7] = fmaxf(fmaf(acc[7], di, qb.w), 0.f);
  float pa = 0.f, pbv = 0.f;
#pragma unroll
  for (int i = 0; i < 8; ++i) {
    pa = fmaf(h[i], sWl[half * 8 + i], pa);
    pbv = fmaf(h[i], sWr[half * 8 + i], pbv);
  }
  // combine channel halves (lanes differing in bit 0)
  pa += __shfl_xor(pa, 1);
  pbv += __shfl_xor(pbv, 1);
  if (quad == 0) {
    p2[n] = pa;
    r2[n] = pbv;
    deg_inv[n] = di;
  }
}

// layer-2 aggregation + output epilogue: linear recs read, 1 LDS atomic per
// record into u[128]; 512 threads for gather-latency hiding.
__global__ __launch_bounds__(512) void k_agg2out(
    const int* __restrict__ gcur, const int* __restrict__ recs,
    const float* __restrict__ p2, const float* __restrict__ r2,
    const float* __restrict__ deg_inv, const float* __restrict__ b2,
    float* __restrict__ out) {
  __shared__ float u[128];
  const int t = threadIdx.x;
  const int kb = blockIdx.x;
  const int b0 = kb * RSZ;
  const int gend = gcur[kb * 16];
  if (t < 128) u[t] = 0.f;
  __syncthreads();

  int r = b0 + t;
  for (; r + 1536 < gend; r += 2048) {
    const int rec0 = recs[r];
    const int rec1 = recs[r + 512];
    const int rec2 = recs[r + 1024];
    const int rec3 = recs[r + 1536];
    const float v0 = p2[rec0 & 0x1FFFF];
    const float v1 = p2[rec1 & 0x1FFFF];
    const float v2 = p2[rec2 & 0x1FFFF];
    const float v3 = p2[rec3 & 0x1FFFF];
    atomicAdd(&u[rec0 >> 17], v0);
    atomicAdd(&u[rec1 >> 17], v1);
    atomicAdd(&u[rec2 >> 17], v2);
    atomicAdd(&u[rec3 >> 17], v3);
  }
  for (; r < gend; r += 512) {
    const int rec = recs[r];
    atomicAdd(&u[rec >> 17], p2[rec & 0x1FFFF]);
  }
  __syncthreads();
  const int n = kb * 128 + t;
  if (t < 128 && n < N_NODES)
    out[n] = fmaf(u[t], deg_inv[n], r2[n] + b2[0]);
}

extern "C" void kernel_launch(void* const* d_in, const int* in_sizes, int n_in,
                              void* d_out, int out_size, void* d_ws,
                              size_t ws_size, hipStream_t stream) {
  const float* x   = (const float*)d_in[0];
  const int*   ei  = (const int*)d_in[1];
  const float* Wl1 = (const float*)d_in[2];
  const float* Wr1 = (const float*)d_in[3];
  const float* b1  = (const float*)d_in[4];
  const float* Wl2 = (const float*)d_in[5];
  const float* Wr2 = (const float*)d_in[6];
  const float* b2  = (const float*)d_in[7];
  float* out = (float*)d_out;

  const size_t N = N_NODES;
  int* wi = (int*)d_ws;
  int* gcur = wi;                                      // NB_F*16
  int* recs = wi + NB_F * 16;                          // NB_F*RSZ
  unsigned short* p1h = (unsigned short*)(recs + (size_t)NB_F * RSZ);
  float* q1b     = (float*)(p1h + 16 * N);   // 16N ushorts = 8N words
  float* p2      = q1b + 16 * N;
  float* r2      = p2 + N;
  float* deg_inv = r2 + N;

  const int nodeBlocks = (N_NODES + 255) / 256;   // 391
  k_init<<<(NB_F + 255) / 256, 256, 0, stream>>>(gcur);
  k_proj1<<<nodeBlocks, 256, 0, stream>>>(x, Wl1, Wr1, b1, p1h, q1b);
  k_bscatter<<<NTILES, 512, 0, stream>>>(ei, gcur, recs);
  k_sortagg1<<<NB_F, 512, 0, stream>>>(gcur, recs, p1h, q1b, Wl2, Wr2, p2, r2,
                                       deg_inv);
  k_agg2out<<<NB_F, 512, 0, stream>>>(gcur, recs, p2, r2, deg_inv, b2, out);
}

// Round 13
// 176.199 us; speedup vs baseline: 1.2488x; 1.0537x over previous
//
#include <hip/hip_runtime.h>

#define N_NODES 100000
#define N_EDGES 3200000
#define NB_F 782                       // fine buckets: 128 dst nodes each
#define RSZ 4992                       // per-bucket record window (max fill ~4500)
#define TILE 6250
#define NTILES 512                     // 512*6250 == 3.2M exactly
#define PRJ_BLOCKS 196                 // ceil(100000/512) proj1 blocks
#define MAXIT 13                       // ceil(TILE/512)
#define MAXB 10                        // ceil(RSZ/512) per-bucket iters

// ---------------------------------------------------------------------------
// Workspace layout (4-byte elements):
//   gcur      NB_F*16 ints (relative cursor/bucket, one per 64B line; memset 0)
//   node_off  NB_F*128     (absolute start of node's run in recs)
//   node_cnt  NB_F*128     (in-degree per node)
//   recs      NB_F*RSZ     (pass A: (local_dst<<17)|src bucket-grouped;
//                           pass B: sortagg1 overwrites with node-sorted src)
//   p1h   16N ushorts = bf16(x @ Wl1^T)   (3.2 MB, L2-resident)
//   q1b   16N floats  = x @ Wr1^T + b1
//   p2 / r2 / deg_inv   N floats each
// ---------------------------------------------------------------------------

__device__ __forceinline__ float bf2f_lo(unsigned int w) {
  return __uint_as_float(w << 16);
}
__device__ __forceinline__ float bf2f_hi(unsigned int w) {
  return __uint_as_float(w & 0xFFFF0000u);
}
__device__ __forceinline__ unsigned short f2bf(float f) {
  unsigned int b = __float_as_uint(f);
  return (unsigned short)((b + 0x7FFFu + ((b >> 16) & 1u)) >> 16);
}

// Fused front kernel: blocks [0,PRJ_BLOCKS) do proj1 (node MLP), blocks
// [PRJ_BLOCKS, PRJ_BLOCKS+NTILES) do the bucketed tile counting-sort scatter.
// The two halves are data-independent; proj1 blocks drain fast and bscatter
// blocks backfill, hiding proj1 entirely.
__global__ __launch_bounds__(512) void k_front(
    const int* __restrict__ ei, const float* __restrict__ x,
    const float* __restrict__ Wl1, const float* __restrict__ Wr1,
    const float* __restrict__ b1, int* __restrict__ gcur,
    int* __restrict__ recs, unsigned short* __restrict__ p1h,
    float* __restrict__ q1b) {
  __shared__ int smem[14818];  // 58 KB, carved per branch
  const int t = threadIdx.x;

  if (blockIdx.x < PRJ_BLOCKS) {
    // ---------------- proj1: p1h = bf16(x@Wl1^T), q1b = x@Wr1^T + b1 -------
    float* sWl = (float*)smem;          // 512
    float* sWr = (float*)smem + 512;    // 512
    float* sb  = (float*)smem + 1024;   // 16
    sWl[t] = Wl1[t];
    sWr[t] = Wr1[t];
    if (t < 16) sb[t] = b1[t];
    __syncthreads();

    const int n = blockIdx.x * 512 + t;
    if (n >= N_NODES) return;

    float xr[32];
    const float4* xp = (const float4*)(x + (size_t)n * 32);
#pragma unroll
    for (int j = 0; j < 8; ++j) {
      float4 v = xp[j];
      xr[4 * j + 0] = v.x;
      xr[4 * j + 1] = v.y;
      xr[4 * j + 2] = v.z;
      xr[4 * j + 3] = v.w;
    }
    float pv[16], qv[16];
#pragma unroll
    for (int hh = 0; hh < 16; ++hh) {
      float a = 0.f, b = 0.f;
#pragma unroll
      for (int i = 0; i < 32; ++i) {
        a = fmaf(xr[i], sWl[hh * 32 + i], a);
        b = fmaf(xr[i], sWr[hh * 32 + i], b);
      }
      pv[hh] = a;
      qv[hh] = b + sb[hh];
    }
    unsigned int w[8];
#pragma unroll
    for (int j = 0; j < 8; ++j)
      w[j] = (unsigned int)f2bf(pv[2 * j]) |
             ((unsigned int)f2bf(pv[2 * j + 1]) << 16);
    uint4* pp = (uint4*)(p1h + (size_t)n * 16);
    pp[0] = make_uint4(w[0], w[1], w[2], w[3]);
    pp[1] = make_uint4(w[4], w[5], w[6], w[7]);
    float4* qp = (float4*)(q1b + (size_t)n * 16);
#pragma unroll
    for (int j = 0; j < 4; ++j)
      qp[j] =
          make_float4(qv[4 * j], qv[4 * j + 1], qv[4 * j + 2], qv[4 * j + 3]);
    return;
  }

  // ---------------- bscatter: tile counting-sort, rank trick --------------
  int* hist  = smem;          // [0,1024)  counts -> exclusive scan (bstart)
  int* rbase = smem + 1024;   // [1024,1806)
  int* seg   = smem + 1806;   // [1806,2318)
  int* stage = smem + 2318;   // [2318,8568)
  int* dlt   = smem + 8568;   // [8568,14818)  per-pos write delta
  for (int i = t; i < 1024; i += 512) hist[i] = 0;
  __syncthreads();

  const int tb = (blockIdx.x - PRJ_BLOCKS) * TILE;
  int rec[MAXIT], aux[MAXIT];  // aux = (bucket<<16) | rank
#pragma unroll
  for (int i = 0; i < MAXIT; ++i) {
    const int pos = t + i * 512;
    if (pos < TILE) {
      const int e = tb + pos;
      const int s = ei[e];
      const int d = ei[N_EDGES + e];
      const int k = d >> 7;
      const int rank = atomicAdd(&hist[k], 1);
      rec[i] = ((d & 127) << 17) | s;
      aux[i] = (k << 16) | rank;
    } else {
      aux[i] = -1;
    }
  }
  __syncthreads();

  // exclusive scan of hist[1024] with 512 threads (2 elems/thread)
  const int s0 = hist[2 * t], s1 = hist[2 * t + 1];
  const int my = s0 + s1;
  seg[t] = my;
  __syncthreads();
#pragma unroll
  for (int o = 1; o < 512; o <<= 1) {
    const int a = (t >= o) ? seg[t - o] : 0;
    __syncthreads();
    seg[t] += a;
    __syncthreads();
  }
  const int ex = seg[t] - my;
  hist[2 * t] = ex;
  hist[2 * t + 1] = ex + s0;
  // global reservation (relative cursor + k*RSZ base)
  {
    const int b = 2 * t;
    if (b < NB_F && s0) rbase[b] = b * RSZ + atomicAdd(&gcur[b * 16], s0);
    if (b + 1 < NB_F && s1)
      rbase[b + 1] = (b + 1) * RSZ + atomicAdd(&gcur[(b + 1) * 16], s1);
  }
  __syncthreads();

  // atomic-free placement + per-pos delta fill (replaces binary search)
#pragma unroll
  for (int i = 0; i < MAXIT; ++i) {
    if (aux[i] >= 0) {
      const int k = aux[i] >> 16;
      const int rank = aux[i] & 0xFFFF;
      stage[hist[k] + rank] = rec[i];
    }
  }
  for (int k2 = t; k2 < NB_F; k2 += 512) {
    const int st = hist[k2];
    const int en = hist[k2 + 1];
    if (en > st) {
      const int dv = rbase[k2] - st;
      for (int p = st; p < en; ++p) dlt[p] = dv;
    }
  }
  __syncthreads();

  // write-out in position order: 2 LDS reads, no dependent chain
  for (int pos = t; pos < TILE; pos += 512) {
    const int idx = dlt[pos] + pos;
    if ((unsigned)idx < (unsigned)(NB_F * RSZ)) recs[idx] = stage[pos];
  }
}

// FUSED per-bucket sort (rank trick) + layer-1 aggregation; also writes the
// node-sorted src list back to recs (coalesced) + node_off/node_cnt for the
// register-accumulating layer-2 kernel.
__global__ __launch_bounds__(512) void k_sortagg1(
    const int* __restrict__ gcur, int* __restrict__ recs,
    const unsigned short* __restrict__ p1h, const float* __restrict__ q1b,
    const float* __restrict__ Wl2, const float* __restrict__ Wr2,
    float* __restrict__ p2, float* __restrict__ r2,
    float* __restrict__ deg_inv, int* __restrict__ node_off,
    int* __restrict__ node_cnt) {
  __shared__ int hist[128];
  __shared__ int nstart[128];
  __shared__ int ssort[RSZ];
  __shared__ float sWl[16], sWr[16];
  const int t = threadIdx.x;
  const int kb = blockIdx.x;
  const int b0 = kb * RSZ;
  const int gend = b0 + gcur[kb * 16];
  if (t < 128) hist[t] = 0;
  if (t < 16) {
    sWl[t] = Wl2[t];
    sWr[t] = Wr2[t];
  }
  __syncthreads();

  int rc[MAXB], ax[MAXB];  // ax = (local<<13) | rank
#pragma unroll
  for (int i = 0; i < MAXB; ++i) {
    const int r = b0 + t + i * 512;
    if (r < gend) {
      const int rec = recs[r];
      const int local = rec >> 17;
      const int rank = atomicAdd(&hist[local], 1);
      rc[i] = rec & 0x1FFFF;
      ax[i] = (local << 13) | rank;
    } else {
      ax[i] = -1;
    }
  }
  __syncthreads();

  // exclusive scan of hist[128] -> nstart
  {
    int v = (t < 128) ? hist[t] : 0;
    if (t < 128) nstart[t] = v;
    __syncthreads();
#pragma unroll
    for (int o = 1; o < 128; o <<= 1) {
      const int a = (t < 128 && t >= o) ? nstart[t - o] : 0;
      __syncthreads();
      if (t < 128) nstart[t] += a;
      __syncthreads();
    }
    if (t < 128) nstart[t] -= v;
  }
  __syncthreads();

  // atomic-free placement into LDS
#pragma unroll
  for (int i = 0; i < MAXB; ++i) {
    if (ax[i] >= 0) ssort[nstart[ax[i] >> 13] + (ax[i] & 0x1FFF)] = rc[i];
  }
  __syncthreads();

  // coalesced write-back: recs now holds node-sorted src ids + CSR metadata
  const int T = gend - b0;
  for (int j2 = t; j2 < T; j2 += 512) recs[b0 + j2] = ssort[j2];
  if (t < 128) {
    node_off[kb * 128 + t] = b0 + nstart[t];
    node_cnt[kb * 128 + t] = hist[t];
  }

  // aggregation: 4 lanes/node; quad = (edge-parity<<1)|channel-half
  const int local = t >> 2;
  const int quad = t & 3;
  const int half = quad & 1;   // channel half (8 channels)
  const int epar = quad >> 1;  // edge parity
  const int n = kb * 128 + local;
  if (n >= N_NODES) return;
  const int st = nstart[local];
  const int k = hist[local];
  const unsigned short* pb = p1h + half * 8;

  float acc[8];
#pragma unroll
  for (int i = 0; i < 8; ++i) acc[i] = 0.f;
  int j = epar;
  for (; j + 6 < k; j += 8) {
    const int s0 = ssort[st + j], s1 = ssort[st + j + 2],
              s2 = ssort[st + j + 4], s3 = ssort[st + j + 6];
    const uint4 w0 = *(const uint4*)(pb + (size_t)s0 * 16);
    const uint4 w1 = *(const uint4*)(pb + (size_t)s1 * 16);
    const uint4 w2 = *(const uint4*)(pb + (size_t)s2 * 16);
    const uint4 w3 = *(const uint4*)(pb + (size_t)s3 * 16);
    acc[0] += (bf2f_lo(w0.x) + bf2f_lo(w1.x)) + (bf2f_lo(w2.x) + bf2f_lo(w3.x));
    acc[1] += (bf2f_hi(w0.x) + bf2f_hi(w1.x)) + (bf2f_hi(w2.x) + bf2f_hi(w3.x));
    acc[2] += (bf2f_lo(w0.y) + bf2f_lo(w1.y)) + (bf2f_lo(w2.y) + bf2f_lo(w3.y));
    acc[3] += (bf2f_hi(w0.y) + bf2f_hi(w1.y)) + (bf2f_hi(w2.y) + bf2f_hi(w3.y));
    acc[4] += (bf2f_lo(w0.z) + bf2f_lo(w1.z)) + (bf2f_lo(w2.z) + bf2f_lo(w3.z));
    acc[5] += (bf2f_hi(w0.z) + bf2f_hi(w1.z)) + (bf2f_hi(w2.z) + bf2f_hi(w3.z));
    acc[6] += (bf2f_lo(w0.w) + bf2f_lo(w1.w)) + (bf2f_lo(w2.w) + bf2f_lo(w3.w));
    acc[7] += (bf2f_hi(w0.w) + bf2f_hi(w1.w)) + (bf2f_hi(w2.w) + bf2f_hi(w3.w));
  }
  for (; j < k; j += 2) {
    const uint4 w = *(const uint4*)(pb + (size_t)ssort[st + j] * 16);
    acc[0] += bf2f_lo(w.x);
    acc[1] += bf2f_hi(w.x);
    acc[2] += bf2f_lo(w.y);
    acc[3] += bf2f_hi(w.y);
    acc[4] += bf2f_lo(w.z);
    acc[5] += bf2f_hi(w.z);
    acc[6] += bf2f_lo(w.w);
    acc[7] += bf2f_hi(w.w);
  }
#pragma unroll
  for (int i = 0; i < 8; ++i) acc[i] += __shfl_xor(acc[i], 2);

  const float di = 1.f / fmaxf((float)k, 1.f);
  const float4* qp = (const float4*)(q1b + (size_t)n * 16 + half * 8);
  const float4 qa = qp[0], qb = qp[1];
  float h[8];
  h[0] = fmaxf(fmaf(acc[0], di, qa.x), 0.f);
  h[1] = fmaxf(fmaf(acc[1], di, qa.y), 0.f);
  h[2] = fmaxf(fmaf(acc[2], di, qa.z), 0.f);
  h[3] = fmaxf(fmaf(acc[3], di, qa.w), 0.f);
  h[4] = fmaxf(fmaf(acc[4], di, qb.x), 0.f);
  h[5] = fmaxf(fmaf(acc[5], di, qb.y), 0.f);
  h[6] = fmaxf(fmaf(acc[6], di, qb.z), 0.f);
  h[7] = fmaxf(fmaf(acc[7], di, qb.w), 0.f);
  float pa = 0.f, pbv = 0.f;
#pragma unroll
  for (int i = 0; i < 8; ++i) {
    pa = fmaf(h[i], sWl[half * 8 + i], pa);
    pbv = fmaf(h[i], sWr[half * 8 + i], pbv);
  }
  pa += __shfl_xor(pa, 1);
  pbv += __shfl_xor(pbv, 1);
  if (quad == 0) {
    p2[n] = pa;
    r2[n] = pbv;
    deg_inv[n] = di;
  }
}

// layer-2 aggregation + output epilogue: node-sorted recs, 4 lanes/node,
// REGISTER accumulation (no LDS atomics).
__global__ __launch_bounds__(512) void k_agg2out(
    const int* __restrict__ node_off, const int* __restrict__ node_cnt,
    const int* __restrict__ recs, const float* __restrict__ p2,
    const float* __restrict__ r2, const float* __restrict__ deg_inv,
    const float* __restrict__ b2, float* __restrict__ out) {
  const int t = threadIdx.x;
  const int n = blockIdx.x * 128 + (t >> 2);
  const int c = t & 3;
  if (n >= N_NODES) return;
  const int k0 = node_off[n];
  const int k = node_cnt[n];
  const int* sl = recs + k0;

  float u = 0.f;
  int j = c;
  for (; j + 4 < k; j += 8) u += p2[sl[j]] + p2[sl[j + 4]];
  for (; j < k; j += 4) u += p2[sl[j]];
  u += __shfl_xor(u, 1);
  u += __shfl_xor(u, 2);
  if (c == 0) out[n] = fmaf(u, deg_inv[n], r2[n] + b2[0]);
}

extern "C" void kernel_launch(void* const* d_in, const int* in_sizes, int n_in,
                              void* d_out, int out_size, void* d_ws,
                              size_t ws_size, hipStream_t stream) {
  const float* x   = (const float*)d_in[0];
  const int*   ei  = (const int*)d_in[1];
  const float* Wl1 = (const float*)d_in[2];
  const float* Wr1 = (const float*)d_in[3];
  const float* b1  = (const float*)d_in[4];
  const float* Wl2 = (const float*)d_in[5];
  const float* Wr2 = (const float*)d_in[6];
  const float* b2  = (const float*)d_in[7];
  float* out = (float*)d_out;

  const size_t N = N_NODES;
  int* wi = (int*)d_ws;
  int* gcur     = wi;                                  // NB_F*16
  int* node_off = wi + NB_F * 16;                      // NB_F*128
  int* node_cnt = node_off + NB_F * 128;               // NB_F*128
  int* recs     = node_cnt + NB_F * 128;               // NB_F*RSZ
  unsigned short* p1h = (unsigned short*)(recs + (size_t)NB_F * RSZ);
  float* q1b     = (float*)(p1h + 16 * N);   // 16N ushorts = 8N words
  float* p2      = q1b + 16 * N;
  float* r2      = p2 + N;
  float* deg_inv = r2 + N;

  hipMemsetAsync(gcur, 0, NB_F * 16 * sizeof(int), stream);
  k_front<<<PRJ_BLOCKS + NTILES, 512, 0, stream>>>(ei, x, Wl1, Wr1, b1, gcur,
                                                   recs, p1h, q1b);
  k_sortagg1<<<NB_F, 512, 0, stream>>>(gcur, recs, p1h, q1b, Wl2, Wr2, p2, r2,
                                       deg_inv, node_off, node_cnt);
  k_agg2out<<<NB_F, 512, 0, stream>>>(node_off, node_cnt, recs, p2, r2,
                                      deg_inv, b2, out);
}